// Round 6
// baseline (314.749 us; speedup 1.0000x reference)
//
#include <hip/hip_runtime.h>
#include <hip/hip_bf16.h>

#define NGRAPH 1024
#define NPG 128
#define EPG 2048
#define ETOT (NGRAPH*NPG*16)

typedef unsigned int uint;
typedef unsigned short ushort_t;
typedef __attribute__((ext_vector_type(8))) short s8v;
typedef __attribute__((ext_vector_type(4))) float f32x4;

#define MFMA16 __builtin_amdgcn_mfma_f32_16x16x32_bf16

__device__ __forceinline__ float lrelu(float x, float s){ return fmaxf(x, x*s); }
__device__ __forceinline__ float b2lo(uint u){ return __uint_as_float(u << 16); }
__device__ __forceinline__ float b2hi(uint u){ return __uint_as_float(u & 0xFFFF0000u); }
__device__ __forceinline__ uint pkbf(float a, float b){
  union { __hip_bfloat162 h; uint u; } t;
  t.h = __hip_bfloat162{__float2bfloat16(a), __float2bfloat16(b)};
  return t.u;
}
__device__ __forceinline__ ushort_t bfb(float v){
  union { __hip_bfloat16 h; ushort_t u; } t; t.h = __float2bfloat16(v); return t.u;
}
union U4S8 { uint4 u; s8v s; };
__device__ __forceinline__ s8v bcs8(uint4 u){ U4S8 t; t.u = u; return t.s; }
#define DPP_ADD(v, ctrl) ((v) + __int_as_float(__builtin_amdgcn_update_dpp(0, __float_as_int(v), (ctrl), 0xF, 0xF, false)))

// bf16 rows of 64 feats (32 u32 pairs), octet-XOR swizzle
__device__ __forceinline__ int oswz(int r, int p){ return (r<<5) | ((((p>>2) ^ (r & 7))<<2) | (p & 3)); }
__device__ __forceinline__ int obase(int r, int oc){ return (r<<5) | (((oc) ^ (r & 7))<<2); }

__device__ __forceinline__ void fma8(float* acc, uint4 q, float a){
  acc[0] += a*b2lo(q.x); acc[1] += a*b2hi(q.x);
  acc[2] += a*b2lo(q.y); acc[3] += a*b2hi(q.y);
  acc[4] += a*b2lo(q.z); acc[5] += a*b2hi(q.z);
  acc[6] += a*b2lo(q.w); acc[7] += a*b2hi(q.w);
}

// LDS map (u32 words): 11713 w = 46852 B -> 3 blocks/CU
#define O_A   0        // 4096: xl / xw        ROW32 [128][32]
#define O_B   4096     // 4096: xr -> h chain  ROW32 [128][32]
#define O_EVA 8192     // 2048: eva f32[2048] (GATv2) / WgT bf16 [64][32pairs]=2048w (GATConv) / spos int[128] (CSR)
#define O_ED  10240    // 1024: edsd u16[2048]
#define O_WS  11264    // 128: was[64]+wad[64]
#define O_SOF 11392    // 65:  soff u16[130]
#define O_ALS 11457    // 128
#define O_ALD 11585    // 128
#define SM_SZ 11713

__global__ __launch_bounds__(256, 3) void gnn_fused(
    const float* __restrict__ x, const int* __restrict__ ei,
    const float* __restrict__ Wl, const float* __restrict__ bl,
    const float* __restrict__ Wr, const float* __restrict__ br,
    const float* __restrict__ att, const float* __restrict__ bv2,
    const float* __restrict__ Wg1, const float* __restrict__ as1,
    const float* __restrict__ ad1, const float* __restrict__ bg1,
    const float* __restrict__ Wg2, const float* __restrict__ as2,
    const float* __restrict__ ad2, const float* __restrict__ bg2,
    const float* __restrict__ lng, const float* __restrict__ lnb,
    uint* __restrict__ hout)
{
  __shared__ uint SM[SM_SZ];
  float*    eva    = (float*)(SM + O_EVA);
  ushort_t* edsL   = (ushort_t*)(SM + O_ED);
  ushort_t* soff16 = (ushort_t*)(SM + O_SOF);
  float*    als    = (float*)(SM + O_ALS);
  float*    ald    = (float*)(SM + O_ALD);
  float*    was    = (float*)(SM + O_WS);
  float*    wad    = was + 64;
  ushort_t* wgA16  = (ushort_t*)(SM + O_A);
  ushort_t* wg16   = (ushort_t*)(SM + O_EVA);   // WgT: 64 rows x 32 pairs = 2048 words (fits eva region)

  const int g    = blockIdx.x;
  const int tid  = threadIdx.x;
  const int lane = tid & 63;
  const int wv   = tid >> 6;
  const int lw   = lane & 15;
  const int lq   = lane >> 4;
  const int sl   = lane & 7;       // sub-lane in 8-group
  const int grp  = lane >> 3;      // 8-lane group id (0..7)
  const int ebase = g * EPG;

  // ================= CSR build (spos aliased into eva region) =================
  {
    int* spos = (int*)(SM + O_EVA);
    if (tid < NPG) spos[tid] = 0;
    __syncthreads();
    for (int e = tid; e < EPG; e += 256)
      atomicAdd(&spos[ei[ETOT + ebase + e] - g*NPG], 1);
    __syncthreads();
    if (wv == 0) {
      int c0 = spos[lane], c1 = spos[lane + 64];
      #pragma unroll
      for (int o = 1; o < 64; o <<= 1) { int t = __shfl_up(c0, o); if (lane >= o) c0 += t; }
      #pragma unroll
      for (int o = 1; o < 64; o <<= 1) { int t = __shfl_up(c1, o); if (lane >= o) c1 += t; }
      int tot0 = __shfl(c0, 63);
      soff16[lane + 1]  = (ushort_t)c0;
      soff16[lane + 65] = (ushort_t)(c1 + tot0);
      if (lane == 0) soff16[0] = 0;
    }
    __syncthreads();
    if (tid < NPG) spos[tid] = soff16[tid];
    __syncthreads();
    for (int e = tid; e < EPG; e += 256) {
      int s = ei[ebase + e] - g*NPG;
      int d = ei[ETOT + ebase + e] - g*NPG;
      int p = atomicAdd(&spos[d], 1);
      edsL[p] = (ushort_t)(s | (d << 8));
    }
    // no barrier yet: transforms below don't touch edsL/spos regions
  }

  // ================= GATv2 transforms: xl -> O_A, xr -> O_B =================
  {
    const int pl = lane & 31, hb = lane >> 5;
    const float2 wl0 = *(const float2*)&Wl[0*64 + 2*pl];
    const float2 wl1 = *(const float2*)&Wl[1*64 + 2*pl];
    const float2 wl2 = *(const float2*)&Wl[2*64 + 2*pl];
    const float2 wl3 = *(const float2*)&Wl[3*64 + 2*pl];
    const float2 wr0 = *(const float2*)&Wr[0*64 + 2*pl];
    const float2 wr1 = *(const float2*)&Wr[1*64 + 2*pl];
    const float2 wr2 = *(const float2*)&Wr[2*64 + 2*pl];
    const float2 wr3 = *(const float2*)&Wr[3*64 + 2*pl];
    const float2 blp = *(const float2*)&bl[2*pl];
    const float2 brp = *(const float2*)&br[2*pl];
    const float4* x4 = (const float4*)x + (size_t)g * NPG;
    for (int st = 0; st < 16; st++) {
      int i = st*8 + wv*2 + hb;
      float4 xi = x4[i];
      float l0 = blp.x + xi.x*wl0.x + xi.y*wl1.x + xi.z*wl2.x + xi.w*wl3.x;
      float l1 = blp.y + xi.x*wl0.y + xi.y*wl1.y + xi.z*wl2.y + xi.w*wl3.y;
      float r0 = brp.x + xi.x*wr0.x + xi.y*wr1.x + xi.z*wr2.x + xi.w*wr3.x;
      float r1 = brp.y + xi.x*wr0.y + xi.y*wr1.y + xi.z*wr2.y + xi.w*wr3.y;
      SM[O_A + oswz(i, pl)] = pkbf(l0, l1);
      SM[O_B + oswz(i, pl)] = pkbf(r0, r1);
    }
  }
  __syncthreads();

  // ================= GATv2 fused (per-wave, NO barriers inside) =================
  // wave owns dst [32wv, 32wv+32); 8-lane group per dst; h' -> O_B over xr[d]
  {
    float4 atA = *(const float4*)&att[sl*8];
    float4 atB = *(const float4*)&att[sl*8 + 4];
    float4 bvA = *(const float4*)&bv2[sl*8];
    float4 bvB = *(const float4*)&bv2[sl*8 + 4];
    for (int pass = 0; pass < 4; pass++) {
      int d  = wv*32 + pass*8 + grp;
      int p0 = soff16[d], p1 = soff16[d+1];
      uint4 qr = *(uint4*)&SM[O_B + obase(d, sl)];
      // --- per-edge logits (group-coop 64-dot), track max
      float m = -1e30f;
      if (p0 < p1) {
        int sN = edsL[p0] & 127;
        uint4 qN = *(uint4*)&SM[O_A + obase(sN, sl)];
        for (int e = p0; e < p1; e++) {
          uint4 ql = qN;
          if (e + 1 < p1) { sN = edsL[e+1] & 127; qN = *(uint4*)&SM[O_A + obase(sN, sl)]; }
          float pt;
          pt  = lrelu(b2lo(ql.x)+b2lo(qr.x), 0.2f)*atA.x;
          pt += lrelu(b2hi(ql.x)+b2hi(qr.x), 0.2f)*atA.y;
          pt += lrelu(b2lo(ql.y)+b2lo(qr.y), 0.2f)*atA.z;
          pt += lrelu(b2hi(ql.y)+b2hi(qr.y), 0.2f)*atA.w;
          pt += lrelu(b2lo(ql.z)+b2lo(qr.z), 0.2f)*atB.x;
          pt += lrelu(b2hi(ql.z)+b2hi(qr.z), 0.2f)*atB.y;
          pt += lrelu(b2lo(ql.w)+b2lo(qr.w), 0.2f)*atB.z;
          pt += lrelu(b2hi(ql.w)+b2hi(qr.w), 0.2f)*atB.w;
          pt += __shfl_xor(pt, 1); pt += __shfl_xor(pt, 2); pt += __shfl_xor(pt, 4);
          if (sl == 0) eva[e] = pt;
          m = fmaxf(m, pt);
        }
      }
      // --- sum of exp
      float ss = 0.f;
      for (int e = p0 + sl; e < p1; e += 8) ss += __expf(eva[e] - m);
      ss += __shfl_xor(ss, 1); ss += __shfl_xor(ss, 2); ss += __shfl_xor(ss, 4);
      float rnm = 1.f / (ss + 1e-16f);
      // --- aggregate (f32 accum, pipelined gathers)
      float acc[8] = {0,0,0,0,0,0,0,0};
      if (p0 < p1) {
        int sN = edsL[p0] & 127;
        uint4 qN = *(uint4*)&SM[O_A + obase(sN, sl)];
        float evN = eva[p0];
        for (int e = p0; e < p1; e++) {
          uint4 ql = qN; float ev = evN;
          if (e + 1 < p1) {
            sN = edsL[e+1] & 127;
            qN = *(uint4*)&SM[O_A + obase(sN, sl)];
            evN = eva[e+1];
          }
          fma8(acc, ql, __expf(ev - m) * rnm);
        }
      }
      uint4 o;
      o.x = pkbf(lrelu(acc[0]+bvA.x,0.01f), lrelu(acc[1]+bvA.y,0.01f));
      o.y = pkbf(lrelu(acc[2]+bvA.z,0.01f), lrelu(acc[3]+bvA.w,0.01f));
      o.z = pkbf(lrelu(acc[4]+bvB.x,0.01f), lrelu(acc[5]+bvB.y,0.01f));
      o.w = pkbf(lrelu(acc[6]+bvB.z,0.01f), lrelu(acc[7]+bvB.w,0.01f));
      *(uint4*)&SM[O_B + obase(d, sl)] = o;
    }
  }
  __syncthreads();

  // ================= LayerNorm in place on O_B =================
  {
    int pl = lane & 31, hb = lane >> 5;
    float2 gv = *(const float2*)&lng[2*pl];
    float2 bv = *(const float2*)&lnb[2*pl];
    for (int it = 0; it < 16; it++) {
      int d = it*8 + wv*2 + hb;
      uint w = SM[O_B + oswz(d, pl)];
      float v0 = b2lo(w), v1 = b2hi(w);
      float s1 = v0 + v1, s2 = v0*v0 + v1*v1;
      #pragma unroll
      for (int o = 1; o < 32; o <<= 1) { s1 += __shfl_xor(s1, o); s2 += __shfl_xor(s2, o); }
      float mu  = s1 * 0.015625f;
      float var = s2 * 0.015625f - mu*mu;
      float rs  = rsqrtf(var + 1e-5f);
      SM[O_B + oswz(d, pl)] = pkbf((v0-mu)*rs*gv.x + bv.x, (v1-mu)*rs*gv.y + bv.y);
    }
  }
  __syncthreads();

  // ================= two GATConv layers =================
  for (int layer = 0; layer < 2; layer++) {
    const float* Wg  = layer ? Wg2 : Wg1;
    const float* avs = layer ? as2 : as1;
    const float* avd = layer ? ad2 : ad1;
    const float* bg  = layer ? bg2 : bg1;

    // --- stage: was/wad = Wg @ a (128 thr); WgT bf16 -> eva region (128 thr)
    if (tid < 128) {
      const float* av = (tid < 64) ? avs : avd;
      float* dst = (tid < 64) ? was : wad;
      int k = tid & 63;
      float acc = 0.f;
      #pragma unroll
      for (int jj = 0; jj < 16; jj++) {
        float4 w = *(const float4*)&Wg[k*64 + jj*4];
        float4 a = *(const float4*)&av[jj*4];
        acc += w.x*a.x + w.y*a.y + w.z*a.z + w.w*a.w;
      }
      dst[k] = acc;
    } else {
      int t2 = tid - 128;
      #pragma unroll
      for (int i = 0; i < 8; i++) {
        int idx = t2 + i*128;
        int k = idx >> 4, j4 = (idx & 15)*4;
        float4 w = *(const float4*)&Wg[k*64 + j4];
        wg16[oswz(j4+0, k>>1)*2 + (k&1)] = bfb(w.x);
        wg16[oswz(j4+1, k>>1)*2 + (k&1)] = bfb(w.y);
        wg16[oswz(j4+2, k>>1)*2 + (k&1)] = bfb(w.z);
        wg16[oswz(j4+3, k>>1)*2 + (k&1)] = bfb(w.w);
      }
    }
    __syncthreads();

    // --- phase2: MFMA transform xw = h @ Wg (node-major -> O_A) + rank-1 als/ald
    {
      int row = 16*wv + lw;   // j-row of WgT
      s8v a0 = bcs8(*(uint4*)&SM[O_EVA + obase(row, lq)]);
      s8v a1 = bcs8(*(uint4*)&SM[O_EVA + obase(row, 4+lq)]);
      int j0 = 16*wv + lq*4;
      #pragma unroll
      for (int nt = 0; nt < 8; nt++) {
        int d = nt*16 + lw;
        s8v b0 = bcs8(*(uint4*)&SM[O_B + obase(d, lq)]);
        s8v b1 = bcs8(*(uint4*)&SM[O_B + obase(d, 4+lq)]);
        f32x4 c = {0.f,0.f,0.f,0.f};
        c = MFMA16(a0, b0, c, 0, 0, 0);
        c = MFMA16(a1, b1, c, 0, 0, 0);
        #pragma unroll
        for (int rg = 0; rg < 4; rg++) {
          int j = j0 + rg;
          wgA16[oswz(d, j>>1)*2 + (j&1)] = bfb(c[rg]);
        }
      }
      // rank-1 attention halves from h (O_B)
      float4 ws0 = *(float4*)&was[sl*8], ws1 = *(float4*)&was[sl*8 + 4];
      float4 wd0 = *(float4*)&wad[sl*8], wd1 = *(float4*)&wad[sl*8 + 4];
      for (int ps = 0; ps < 4; ps++) {
        int n = ps*32 + (tid >> 3);
        uint4 q = *(uint4*)&SM[O_B + obase(n, sl)];
        float f0=b2lo(q.x), f1=b2hi(q.x), f2=b2lo(q.y), f3=b2hi(q.y);
        float f4=b2lo(q.z), f5=b2hi(q.z), f6=b2lo(q.w), f7=b2hi(q.w);
        float sa = f0*ws0.x+f1*ws0.y+f2*ws0.z+f3*ws0.w+f4*ws1.x+f5*ws1.y+f6*ws1.z+f7*ws1.w;
        float sd = f0*wd0.x+f1*wd0.y+f2*wd0.z+f3*wd0.w+f4*wd1.x+f5*wd1.y+f6*wd1.z+f7*wd1.w;
        sa = DPP_ADD(sa, 0x111); sa = DPP_ADD(sa, 0x112); sa = DPP_ADD(sa, 0x114);
        sd = DPP_ADD(sd, 0x111); sd = DPP_ADD(sd, 0x112); sd = DPP_ADD(sd, 0x114);
        if ((lane & 7) == 7) { als[n] = sa; ald[n] = sd; }
      }
    }
    __syncthreads();

    // --- fused softmax+aggregate (per-wave, NO barriers inside), h' -> O_B
    {
      float4 bgA = *(const float4*)&bg[sl*8];
      float4 bgB = *(const float4*)&bg[sl*8 + 4];
      for (int pass = 0; pass < 4; pass++) {
        int d  = wv*32 + pass*8 + grp;
        int p0 = soff16[d], p1 = soff16[d+1];
        float ald_d = ald[d];
        float lgs = lrelu(als[d] + ald_d, 0.2f);   // self logit
        // max
        float m = lgs;
        for (int e = p0 + sl; e < p1; e += 8)
          m = fmaxf(m, lrelu(als[edsL[e] & 127] + ald_d, 0.2f));
        m = fmaxf(m, __shfl_xor(m, 1)); m = fmaxf(m, __shfl_xor(m, 2)); m = fmaxf(m, __shfl_xor(m, 4));
        // sum
        float ex0 = __expf(lgs - m);
        float ss = (sl == 0) ? ex0 : 0.f;
        for (int e = p0 + sl; e < p1; e += 8)
          ss += __expf(lrelu(als[edsL[e] & 127] + ald_d, 0.2f) - m);
        ss += __shfl_xor(ss, 1); ss += __shfl_xor(ss, 2); ss += __shfl_xor(ss, 4);
        float rnm = 1.f / (ss + 1e-16f);
        // aggregate: self + edges (pipelined)
        float acc[8] = {0,0,0,0,0,0,0,0};
        fma8(acc, *(uint4*)&SM[O_A + obase(d, sl)], ex0 * rnm);
        if (p0 < p1) {
          int sN = edsL[p0] & 127;
          float alN = als[sN];
          uint4 qN = *(uint4*)&SM[O_A + obase(sN, sl)];
          for (int e = p0; e < p1; e++) {
            uint4 ql = qN; float alv = alN;
            if (e + 1 < p1) {
              sN = edsL[e+1] & 127;
              alN = als[sN];
              qN = *(uint4*)&SM[O_A + obase(sN, sl)];
            }
            fma8(acc, ql, __expf(lrelu(alv + ald_d, 0.2f) - m) * rnm);
          }
        }
        uint4 o;
        o.x = pkbf(fmaxf(acc[0]+bgA.x,0.f), fmaxf(acc[1]+bgA.y,0.f));
        o.y = pkbf(fmaxf(acc[2]+bgA.z,0.f), fmaxf(acc[3]+bgA.w,0.f));
        o.z = pkbf(fmaxf(acc[4]+bgB.x,0.f), fmaxf(acc[5]+bgB.y,0.f));
        o.w = pkbf(fmaxf(acc[6]+bgB.z,0.f), fmaxf(acc[7]+bgB.w,0.f));
        *(uint4*)&SM[O_B + obase(d, sl)] = o;
      }
    }
    __syncthreads();
  }

  // ================= write h (bf16 pairs, node-major) =================
  {
    uint* hg = hout + (size_t)g * 4096;
    #pragma unroll
    for (int i = 0; i < 16; i++) {
      int idx = tid + i*256;
      hg[idx] = SM[O_B + oswz(idx >> 5, idx & 31)];
    }
  }
}

// ---------------- W1 -> W1T bf16 pair transpose ----------------
__global__ __launch_bounds__(256) void w1_transpose(const float* __restrict__ W1,
                                                    uint* __restrict__ w1t)
{
  __shared__ float sw[64*130];
  const int tid = threadIdx.x;
  const int k0 = blockIdx.x * 64;
  #pragma unroll
  for (int i = 0; i < 8; i++) {
    int idx = tid + i*256;
    int r = idx >> 5, c4 = (idx & 31)*4;
    *(float4*)&sw[r*130 + c4] = *(const float4*)&W1[(size_t)(k0+r)*128 + c4];
  }
  __syncthreads();
  #pragma unroll
  for (int i = 0; i < 16; i++) {
    int idx = tid + i*256;
    int c = idx >> 5, kp = idx & 31;
    w1t[(size_t)c*4096 + (k0>>1) + kp] = pkbf(sw[(2*kp)*130 + c], sw[(2*kp+1)*130 + c]);
  }
}

// ---------------- head GEMM: MFMA, split-K 16 ----------------
__global__ __launch_bounds__(256) void head_gemm(
    const uint* __restrict__ hbuf, const uint* __restrict__ w1t,
    float* __restrict__ partial)
{
  __shared__ uint sAh[2048];
  __shared__ uint sBh[4096];
  const int tid = threadIdx.x, lane = tid & 63, wv = tid >> 6;
  const int lw = lane & 15, lq = lane >> 4;
  const int g0 = blockIdx.x * 64;
  const int ks = blockIdx.y;
  f32x4 acc[8];
  #pragma unroll
  for (int i = 0; i < 8; i++) acc[i] = f32x4{0.f,0.f,0.f,0.f};

  for (int ch = 0; ch < 8; ch++) {
    int pb = ks*256 + ch*32;
    #pragma unroll
    for (int i = 0; i < 2; i++) {
      int idx = tid + i*256; int r = idx >> 3, q4 = idx & 7;
      uint4 v = *(const uint4*)&hbuf[(size_t)(g0+r)*4096 + pb + q4*4];
      *(uint4*)&sAh[(r<<5) | ((q4 ^ (r & 7))<<2)] = v;
    }
    #pragma unroll
    for (int i = 0; i < 4; i++) {
      int idx = tid + i*256; int r = idx >> 3, q4 = idx & 7;
      uint4 v = *(const uint4*)&w1t[(size_t)r*4096 + pb + q4*4];
      *(uint4*)&sBh[(r<<5) | ((q4 ^ (r & 7))<<2)] = v;
    }
    __syncthreads();
    int ra = 16*wv + lw;
    s8v a0 = bcs8(*(uint4*)&sAh[obase(ra, lq)]);
    s8v a1 = bcs8(*(uint4*)&sAh[obase(ra, 4+lq)]);
    #pragma unroll
    for (int nt = 0; nt < 8; nt++) {
      int c = nt*16 + lw;
      s8v b0 = bcs8(*(uint4*)&sBh[obase(c, lq)]);
      s8v b1 = bcs8(*(uint4*)&sBh[obase(c, 4+lq)]);
      acc[nt] = MFMA16(a0, b0, acc[nt], 0, 0, 0);
      acc[nt] = MFMA16(a1, b1, acc[nt], 0, 0, 0);
    }
    __syncthreads();
  }
  float* pp = partial + (size_t)ks*131072;
  #pragma unroll
  for (int nt = 0; nt < 8; nt++) {
    int c = nt*16 + lw;
    int r0 = g0 + 16*wv + lq*4;
    #pragma unroll
    for (int rg = 0; rg < 4; rg++)
      pp[(size_t)(r0+rg)*128 + c] = acc[nt][rg];
  }
}

// ---------------- head epilogue: 8 graphs/block, float4 coalesced ----------------
__global__ __launch_bounds__(256) void head_out(
    const float* __restrict__ partial, const float* __restrict__ b1,
    const float* __restrict__ W2, const float* __restrict__ b2,
    float* __restrict__ out)
{
  const int tid = threadIdx.x;
  const int gl  = tid >> 5;           // 0..7
  const int c4  = tid & 31;           // float4 column
  const int g   = blockIdx.x*8 + gl;
  float4 v = *(const float4*)&b1[c4*4];
  #pragma unroll
  for (int s = 0; s < 16; s++) {
    float4 p = *(const float4*)&partial[(size_t)s*131072 + (size_t)g*128 + c4*4];
    v.x += p.x; v.y += p.y; v.z += p.z; v.w += p.w;
  }
  float4 w = *(const float4*)&W2[c4*4];
  float t = lrelu(v.x,0.01f)*w.x + lrelu(v.y,0.01f)*w.y
          + lrelu(v.z,0.01f)*w.z + lrelu(v.w,0.01f)*w.w;
  #pragma unroll
  for (int m = 1; m < 32; m <<= 1) t += __shfl_xor(t, m);
  if (c4 == 0) out[g] = 1.f / (1.f + __expf(-(t + b2[0])));
}

extern "C" void kernel_launch(void* const* d_in, const int* in_sizes, int n_in,
                              void* d_out, int out_size, void* d_ws, size_t ws_size,
                              hipStream_t stream) {
  const float* x   = (const float*)d_in[0];
  const int*   ei  = (const int*)  d_in[1];
  const float* Wl  = (const float*)d_in[2];
  const float* bl_ = (const float*)d_in[3];
  const float* Wr  = (const float*)d_in[4];
  const float* br_ = (const float*)d_in[5];
  const float* att = (const float*)d_in[6];
  const float* bv2 = (const float*)d_in[7];
  const float* Wg1 = (const float*)d_in[8];
  const float* as1 = (const float*)d_in[9];
  const float* ad1 = (const float*)d_in[10];
  const float* bg1 = (const float*)d_in[11];
  const float* Wg2 = (const float*)d_in[12];
  const float* as2 = (const float*)d_in[13];
  const float* ad2 = (const float*)d_in[14];
  const float* bg2 = (const float*)d_in[15];
  const float* lng = (const float*)d_in[16];
  const float* lnb = (const float*)d_in[17];
  const float* W1  = (const float*)d_in[18];
  const float* b1  = (const float*)d_in[19];
  const float* W2  = (const float*)d_in[20];
  const float* b2  = (const float*)d_in[21];
  float* out = (float*)d_out;

  uint*  hbuf    = (uint*)d_ws;                                      // 16 MB
  float* partial = (float*)((char*)d_ws + (size_t)16*1024*1024);     // 8 MB
  uint*  w1t     = (uint*)((char*)d_ws + (size_t)24*1024*1024);      // 2 MB

  w1_transpose<<<128, 256, 0, stream>>>(W1, w1t);
  gnn_fused<<<NGRAPH, 256, 0, stream>>>(x, ei, Wl, bl_, Wr, br_, att, bv2,
      Wg1, as1, ad1, bg1, Wg2, as2, ad2, bg2, lng, lnb, hbuf);
  head_gemm<<<dim3(16, 16), 256, 0, stream>>>(hbuf, w1t, partial);
  head_out<<<128, 256, 0, stream>>>(partial, b1, W2, b2, out);
}

// Round 7
// 310.182 us; speedup vs baseline: 1.0147x; 1.0147x over previous
//
#include <hip/hip_runtime.h>
#include <hip/hip_bf16.h>
#include <hip/hip_fp16.h>

#define NGRAPH 1024
#define NPG 128
#define EPG 2048
#define ETOT (NGRAPH*NPG*16)

typedef unsigned int uint;
typedef unsigned short ushort_t;
typedef __attribute__((ext_vector_type(2))) _Float16 h2v;
typedef __attribute__((ext_vector_type(8))) _Float16 h8v;
typedef __attribute__((ext_vector_type(4))) float f32x4;

#define MFMA16H __builtin_amdgcn_mfma_f32_16x16x32_f16
#define FDOT2(a,b,c) __builtin_amdgcn_fdot2((a),(b),(c),false)

union U1H2 { uint u; h2v h; };
union U4H8 { uint4 u; h8v h; };
union U4H2 { uint4 u; h2v h[4]; };

__device__ __forceinline__ float lrelu(float x, float s){ return fmaxf(x, x*s); }
__device__ __forceinline__ uint pkh(float a, float b){
  U1H2 t; t.h.x = (_Float16)a; t.h.y = (_Float16)b; return t.u;
}
__device__ __forceinline__ ushort_t hfb(float v){
  union { _Float16 h; ushort_t u; } t; t.h = (_Float16)v; return t.u;
}
__device__ __forceinline__ float2 uph(uint u){
  U1H2 t; t.u = u;
  return float2{(float)t.h.x, (float)t.h.y};
}
#define DPP_ADD(v, ctrl) ((v) + __int_as_float(__builtin_amdgcn_update_dpp(0, __float_as_int(v), (ctrl), 0xF, 0xF, false)))

// fp16 rows of 64 feats (32 u32 pair-words), octet-XOR swizzle
__device__ __forceinline__ int oswz(int r, int p){ return (r<<5) | ((((p>>2) ^ (r & 7))<<2) | (p & 3)); }
__device__ __forceinline__ int obase(int r, int oc){ return (r<<5) | (((oc) ^ (r & 7))<<2); }

__device__ __forceinline__ void fma8(float* acc, uint4 q, float a){
  float2 f0 = uph(q.x), f1 = uph(q.y), f2 = uph(q.z), f3 = uph(q.w);
  acc[0] += a*f0.x; acc[1] += a*f0.y;
  acc[2] += a*f1.x; acc[3] += a*f1.y;
  acc[4] += a*f2.x; acc[5] += a*f2.y;
  acc[6] += a*f3.x; acc[7] += a*f3.y;
}

// leaky(xl+xr) dot att for one fp16 pair: leaky(v) = 0.6v + 0.4|v|
__device__ __forceinline__ float dotp(uint ul, uint ur, h2v a2, float acc){
  U1H2 l, r; l.u = ul; r.u = ur;
  h2v v = l.h + r.h;
  U1H2 sv; sv.h = v;
  U1H2 av; av.u = sv.u & 0x7FFF7FFFu;
  h2v c6; c6.x = (_Float16)0.6f; c6.y = (_Float16)0.6f;
  h2v c4; c4.x = (_Float16)0.4f; c4.y = (_Float16)0.4f;
  h2v w = v * c6 + av.h * c4;
  return FDOT2(w, a2, acc);
}

// LDS map (u32 words): 11713 w = 46852 B -> 3 blocks/CU
#define O_A   0        // 4096: xl / xw        ROW32 [128][32]
#define O_B   4096     // 4096: xr -> h chain  ROW32 [128][32]
#define O_EVA 8192     // 2048: eva f32[2048] / WgT f16 [64][32pairs] / spos int[128]
#define O_ED  10240    // 1024: edsd u16[2048]
#define O_WS  11264    // 128: was[64]+wad[64]
#define O_SOF 11392    // 65:  soff u16[130]
#define O_ALS 11457    // 128: als / GATv2 rnm / GATConv selfw
#define O_ALD 11585    // 128: ald / GATConv rnm
#define SM_SZ 11713

__global__ __launch_bounds__(256, 3) void gnn_fused(
    const float* __restrict__ x, const int* __restrict__ ei,
    const float* __restrict__ Wl, const float* __restrict__ bl,
    const float* __restrict__ Wr, const float* __restrict__ br,
    const float* __restrict__ att, const float* __restrict__ bv2,
    const float* __restrict__ Wg1, const float* __restrict__ as1,
    const float* __restrict__ ad1, const float* __restrict__ bg1,
    const float* __restrict__ Wg2, const float* __restrict__ as2,
    const float* __restrict__ ad2, const float* __restrict__ bg2,
    const float* __restrict__ lng, const float* __restrict__ lnb,
    uint* __restrict__ hout)
{
  __shared__ uint SM[SM_SZ];
  float*    eva    = (float*)(SM + O_EVA);
  ushort_t* edsL   = (ushort_t*)(SM + O_ED);
  ushort_t* soff16 = (ushort_t*)(SM + O_SOF);
  float*    als    = (float*)(SM + O_ALS);
  float*    ald    = (float*)(SM + O_ALD);
  float*    was    = (float*)(SM + O_WS);
  float*    wad    = was + 64;
  ushort_t* wgA16  = (ushort_t*)(SM + O_A);
  ushort_t* wg16   = (ushort_t*)(SM + O_EVA);

  const int g    = blockIdx.x;
  const int tid  = threadIdx.x;
  const int lane = tid & 63;
  const int wv   = tid >> 6;
  const int lw   = lane & 15;
  const int lq   = lane >> 4;
  const int sl   = lane & 7;
  const int grp  = lane >> 3;
  const int ebase = g * EPG;

  // ================= CSR build =================
  {
    int* spos = (int*)(SM + O_EVA);
    if (tid < NPG) spos[tid] = 0;
    __syncthreads();
    for (int e = tid; e < EPG; e += 256)
      atomicAdd(&spos[ei[ETOT + ebase + e] - g*NPG], 1);
    __syncthreads();
    if (wv == 0) {
      int c0 = spos[lane], c1 = spos[lane + 64];
      #pragma unroll
      for (int o = 1; o < 64; o <<= 1) { int t = __shfl_up(c0, o); if (lane >= o) c0 += t; }
      #pragma unroll
      for (int o = 1; o < 64; o <<= 1) { int t = __shfl_up(c1, o); if (lane >= o) c1 += t; }
      int tot0 = __shfl(c0, 63);
      soff16[lane + 1]  = (ushort_t)c0;
      soff16[lane + 65] = (ushort_t)(c1 + tot0);
      if (lane == 0) soff16[0] = 0;
    }
    __syncthreads();
    if (tid < NPG) spos[tid] = soff16[tid];
    __syncthreads();
    for (int e = tid; e < EPG; e += 256) {
      int s = ei[ebase + e] - g*NPG;
      int d = ei[ETOT + ebase + e] - g*NPG;
      int p = atomicAdd(&spos[d], 1);
      edsL[p] = (ushort_t)(s | (d << 8));
    }
  }

  // ================= GATv2 transforms: xl -> O_A, xr -> O_B (fp16) =================
  {
    const int pl = lane & 31, hb = lane >> 5;
    const float2 wl0 = *(const float2*)&Wl[0*64 + 2*pl];
    const float2 wl1 = *(const float2*)&Wl[1*64 + 2*pl];
    const float2 wl2 = *(const float2*)&Wl[2*64 + 2*pl];
    const float2 wl3 = *(const float2*)&Wl[3*64 + 2*pl];
    const float2 wr0 = *(const float2*)&Wr[0*64 + 2*pl];
    const float2 wr1 = *(const float2*)&Wr[1*64 + 2*pl];
    const float2 wr2 = *(const float2*)&Wr[2*64 + 2*pl];
    const float2 wr3 = *(const float2*)&Wr[3*64 + 2*pl];
    const float2 blp = *(const float2*)&bl[2*pl];
    const float2 brp = *(const float2*)&br[2*pl];
    const float4* x4 = (const float4*)x + (size_t)g * NPG;
    for (int st = 0; st < 16; st++) {
      int i = st*8 + wv*2 + hb;
      float4 xi = x4[i];
      float l0 = blp.x + xi.x*wl0.x + xi.y*wl1.x + xi.z*wl2.x + xi.w*wl3.x;
      float l1 = blp.y + xi.x*wl0.y + xi.y*wl1.y + xi.z*wl2.y + xi.w*wl3.y;
      float r0 = brp.x + xi.x*wr0.x + xi.y*wr1.x + xi.z*wr2.x + xi.w*wr3.x;
      float r1 = brp.y + xi.x*wr0.y + xi.y*wr1.y + xi.z*wr2.y + xi.w*wr3.y;
      SM[O_A + oswz(i, pl)] = pkh(l0, l1);
      SM[O_B + oswz(i, pl)] = pkh(r0, r1);
    }
  }
  __syncthreads();   // covers CSR scatter + transforms

  // ================= GATv2 edge logits: EDGE-PARALLEL, pk-f16 + fdot2 ============
  {
    h2v att2[32];
    #pragma unroll
    for (int p2 = 0; p2 < 32; p2++) {
      att2[p2].x = (_Float16)att[2*p2];
      att2[p2].y = (_Float16)att[2*p2 + 1];
    }
    for (int it = 0; it < 8; it++) {
      int e  = tid + it*256;
      int sd = edsL[e];
      int s  = sd & 127, d = sd >> 8;
      float acc = 0.f;
      #pragma unroll
      for (int c = 0; c < 8; c++) {
        uint4 ql = *(uint4*)&SM[O_A + obase(s, c)];
        uint4 qr = *(uint4*)&SM[O_B + obase(d, c)];
        acc = dotp(ql.x, qr.x, att2[4*c+0], acc);
        acc = dotp(ql.y, qr.y, att2[4*c+1], acc);
        acc = dotp(ql.z, qr.z, att2[4*c+2], acc);
        acc = dotp(ql.w, qr.w, att2[4*c+3], acc);
      }
      eva[e] = acc;
    }
  }
  __syncthreads();

  // ================= GATv2 softmax (16 lanes/dst): eva <- exp, als <- 1/sum ======
  {
    const int dd = tid >> 4, sl16 = tid & 15;
    for (int it = 0; it < 8; it++) {
      int d = it*16 + dd;
      int p0 = soff16[d], p1 = soff16[d+1];
      float m = -1e30f;
      for (int p = p0 + sl16; p < p1; p += 16) m = fmaxf(m, eva[p]);
      #pragma unroll
      for (int o = 1; o < 16; o <<= 1) m = fmaxf(m, __shfl_xor(m, o));
      float ss = 0.f;
      for (int p = p0 + sl16; p < p1; p += 16) {
        float ex = __expf(eva[p] - m); ss += ex; eva[p] = ex;
      }
      #pragma unroll
      for (int o = 1; o < 16; o <<= 1) ss += __shfl_xor(ss, o);
      if (sl16 == 0) als[d] = 1.f / (ss + 1e-16f);
    }
  }
  __syncthreads();

  // ================= GATv2 aggregate (group/dst, precomputed weights) ============
  {
    float2 bvA = *(const float2*)&bv2[sl*8];
    float2 bvB = *(const float2*)&bv2[sl*8 + 2];
    float2 bvC = *(const float2*)&bv2[sl*8 + 4];
    float2 bvD = *(const float2*)&bv2[sl*8 + 6];
    for (int pass = 0; pass < 4; pass++) {
      int d  = wv*32 + pass*8 + grp;
      int p0 = soff16[d], p1 = soff16[d+1];
      float acc[8] = {0,0,0,0,0,0,0,0};
      if (p0 < p1) {
        int sN = edsL[p0] & 127;
        uint4 qN = *(uint4*)&SM[O_A + obase(sN, sl)];
        float wN = eva[p0];
        for (int e = p0; e < p1; e++) {
          uint4 ql = qN; float w = wN;
          if (e + 1 < p1) {
            sN = edsL[e+1] & 127;
            qN = *(uint4*)&SM[O_A + obase(sN, sl)];
            wN = eva[e+1];
          }
          fma8(acc, ql, w);
        }
      }
      float nm = als[d];
      uint4 o;
      o.x = pkh(lrelu(acc[0]*nm+bvA.x,0.01f), lrelu(acc[1]*nm+bvA.y,0.01f));
      o.y = pkh(lrelu(acc[2]*nm+bvB.x,0.01f), lrelu(acc[3]*nm+bvB.y,0.01f));
      o.z = pkh(lrelu(acc[4]*nm+bvC.x,0.01f), lrelu(acc[5]*nm+bvC.y,0.01f));
      o.w = pkh(lrelu(acc[6]*nm+bvD.x,0.01f), lrelu(acc[7]*nm+bvD.y,0.01f));
      *(uint4*)&SM[O_B + obase(d, sl)] = o;
    }
  }
  __syncthreads();

  // ================= LayerNorm in place on O_B (fdot2 sums) =================
  {
    int pl = lane & 31, hb = lane >> 5;
    float2 gv = *(const float2*)&lng[2*pl];
    float2 bv = *(const float2*)&lnb[2*pl];
    h2v one2; one2.x = (_Float16)1.f; one2.y = (_Float16)1.f;
    for (int it = 0; it < 16; it++) {
      int d = it*8 + wv*2 + hb;
      uint w = SM[O_B + oswz(d, pl)];
      U1H2 t; t.u = w;
      float s1 = FDOT2(t.h, one2, 0.f);
      float s2 = FDOT2(t.h, t.h, 0.f);
      #pragma unroll
      for (int o = 1; o < 32; o <<= 1) { s1 += __shfl_xor(s1, o); s2 += __shfl_xor(s2, o); }
      float mu  = s1 * 0.015625f;
      float var = s2 * 0.015625f - mu*mu;
      float rs  = rsqrtf(var + 1e-5f);
      float2 f = uph(w);
      SM[O_B + oswz(d, pl)] = pkh((f.x-mu)*rs*gv.x + bv.x, (f.y-mu)*rs*gv.y + bv.y);
    }
  }
  __syncthreads();

  // ================= two GATConv layers =================
  for (int layer = 0; layer < 2; layer++) {
    const float* Wg  = layer ? Wg2 : Wg1;
    const float* avs = layer ? as2 : as1;
    const float* avd = layer ? ad2 : ad1;
    const float* bg  = layer ? bg2 : bg1;

    // --- stage: was/wad = Wg @ a ; WgT fp16 -> eva region
    if (tid < 128) {
      const float* av = (tid < 64) ? avs : avd;
      float* dst = (tid < 64) ? was : wad;
      int k = tid & 63;
      float acc = 0.f;
      #pragma unroll
      for (int jj = 0; jj < 16; jj++) {
        float4 w = *(const float4*)&Wg[k*64 + jj*4];
        float4 a = *(const float4*)&av[jj*4];
        acc += w.x*a.x + w.y*a.y + w.z*a.z + w.w*a.w;
      }
      dst[k] = acc;
    } else {
      int t2 = tid - 128;
      #pragma unroll
      for (int i = 0; i < 8; i++) {
        int idx = t2 + i*128;
        int k = idx >> 4, j4 = (idx & 15)*4;
        float4 w = *(const float4*)&Wg[k*64 + j4];
        wg16[oswz(j4+0, k>>1)*2 + (k&1)] = hfb(w.x);
        wg16[oswz(j4+1, k>>1)*2 + (k&1)] = hfb(w.y);
        wg16[oswz(j4+2, k>>1)*2 + (k&1)] = hfb(w.z);
        wg16[oswz(j4+3, k>>1)*2 + (k&1)] = hfb(w.w);
      }
    }
    __syncthreads();

    // --- MFMA transform xw = h @ Wg -> O_A ; rank-1 als/ald via fdot2
    {
      U4H8 a0t, a1t;
      a0t.u = *(uint4*)&SM[O_EVA + obase(16*wv + lw, lq)];
      a1t.u = *(uint4*)&SM[O_EVA + obase(16*wv + lw, 4+lq)];
      int j0 = 16*wv + lq*4;
      #pragma unroll
      for (int nt = 0; nt < 8; nt++) {
        int d = nt*16 + lw;
        U4H8 b0t, b1t;
        b0t.u = *(uint4*)&SM[O_B + obase(d, lq)];
        b1t.u = *(uint4*)&SM[O_B + obase(d, 4+lq)];
        f32x4 c = {0.f,0.f,0.f,0.f};
        c = MFMA16H(a0t.h, b0t.h, c, 0, 0, 0);
        c = MFMA16H(a1t.h, b1t.h, c, 0, 0, 0);
        #pragma unroll
        for (int rg = 0; rg < 4; rg++) {
          int j = j0 + rg;
          wgA16[oswz(d, j>>1)*2 + (j&1)] = hfb(c[rg]);
        }
      }
      // rank-1 attention halves (fdot2 over fp16 pairs)
      h2v ws2[4], wd2[4];
      #pragma unroll
      for (int q2 = 0; q2 < 4; q2++) {
        float2 a = *(float2*)&was[sl*8 + 2*q2];
        float2 b = *(float2*)&wad[sl*8 + 2*q2];
        ws2[q2].x = (_Float16)a.x; ws2[q2].y = (_Float16)a.y;
        wd2[q2].x = (_Float16)b.x; wd2[q2].y = (_Float16)b.y;
      }
      for (int ps = 0; ps < 4; ps++) {
        int n = ps*32 + (tid >> 3);
        U4H2 q; q.u = *(uint4*)&SM[O_B + obase(n, sl)];
        float sa = 0.f, sd = 0.f;
        #pragma unroll
        for (int q2 = 0; q2 < 4; q2++) {
          sa = FDOT2(q.h[q2], ws2[q2], sa);
          sd = FDOT2(q.h[q2], wd2[q2], sd);
        }
        sa = DPP_ADD(sa, 0x111); sa = DPP_ADD(sa, 0x112); sa = DPP_ADD(sa, 0x114);
        sd = DPP_ADD(sd, 0x111); sd = DPP_ADD(sd, 0x112); sd = DPP_ADD(sd, 0x114);
        if ((lane & 7) == 7) { als[n] = sa; ald[n] = sd; }
      }
    }
    __syncthreads();

    // --- edge logits EDGE-PARALLEL (rank-1), raw -> eva
    for (int it = 0; it < 8; it++) {
      int e  = tid + it*256;
      int sd = edsL[e];
      eva[e] = lrelu(als[sd & 127] + ald[sd >> 8], 0.2f);
    }
    __syncthreads();

    // --- softmax incl self (16 lanes/dst): eva <- exp, als <- self exp, ald <- 1/sum
    {
      const int dd = tid >> 4, sl16 = tid & 15;
      for (int it = 0; it < 8; it++) {
        int d = it*16 + dd;
        int p0 = soff16[d], p1 = soff16[d+1];
        float lgs = lrelu(als[d] + ald[d], 0.2f);
        float m = lgs;
        for (int p = p0 + sl16; p < p1; p += 16) m = fmaxf(m, eva[p]);
        #pragma unroll
        for (int o = 1; o < 16; o <<= 1) m = fmaxf(m, __shfl_xor(m, o));
        float ex0 = __expf(lgs - m);
        float ss = 0.f;
        for (int p = p0 + sl16; p < p1; p += 16) {
          float ex = __expf(eva[p] - m); ss += ex; eva[p] = ex;
        }
        #pragma unroll
        for (int o = 1; o < 16; o <<= 1) ss += __shfl_xor(ss, o);
        if (sl16 == 0) {
          als[d] = ex0;
          ald[d] = 1.f / (ss + ex0 + 1e-16f);
        }
      }
    }
    __syncthreads();

    // --- aggregate incl self (group/dst, precomputed weights), bias+relu -> O_B
    {
      float2 bgA = *(const float2*)&bg[sl*8];
      float2 bgB = *(const float2*)&bg[sl*8 + 2];
      float2 bgC = *(const float2*)&bg[sl*8 + 4];
      float2 bgD = *(const float2*)&bg[sl*8 + 6];
      for (int pass = 0; pass < 4; pass++) {
        int d  = wv*32 + pass*8 + grp;
        int p0 = soff16[d], p1 = soff16[d+1];
        float acc[8] = {0,0,0,0,0,0,0,0};
        fma8(acc, *(uint4*)&SM[O_A + obase(d, sl)], als[d]);   // self
        if (p0 < p1) {
          int sN = edsL[p0] & 127;
          uint4 qN = *(uint4*)&SM[O_A + obase(sN, sl)];
          float wN = eva[p0];
          for (int e = p0; e < p1; e++) {
            uint4 ql = qN; float w = wN;
            if (e + 1 < p1) {
              sN = edsL[e+1] & 127;
              qN = *(uint4*)&SM[O_A + obase(sN, sl)];
              wN = eva[e+1];
            }
            fma8(acc, ql, w);
          }
        }
        float nm = ald[d];
        uint4 o;
        o.x = pkh(fmaxf(acc[0]*nm+bgA.x,0.f), fmaxf(acc[1]*nm+bgA.y,0.f));
        o.y = pkh(fmaxf(acc[2]*nm+bgB.x,0.f), fmaxf(acc[3]*nm+bgB.y,0.f));
        o.z = pkh(fmaxf(acc[4]*nm+bgC.x,0.f), fmaxf(acc[5]*nm+bgC.y,0.f));
        o.w = pkh(fmaxf(acc[6]*nm+bgD.x,0.f), fmaxf(acc[7]*nm+bgD.y,0.f));
        *(uint4*)&SM[O_B + obase(d, sl)] = o;
      }
    }
    __syncthreads();
  }

  // ================= write h (fp16 pairs, node-major) =================
  {
    uint* hg = hout + (size_t)g * 4096;
    #pragma unroll
    for (int i = 0; i < 16; i++) {
      int idx = tid + i*256;
      hg[idx] = SM[O_B + oswz(idx >> 5, idx & 31)];
    }
  }
}

// ---------------- head GEMM: MFMA f16, split-K 16, in-kernel W1 transpose -------
__global__ __launch_bounds__(256) void head_gemm(
    const uint* __restrict__ hbuf, const float* __restrict__ W1,
    float* __restrict__ partial)
{
  __shared__ uint sAh[2048];
  __shared__ uint sBh[4096];
  const int tid = threadIdx.x, lane = tid & 63, wv = tid >> 6;
  const int lw = lane & 15, lq = lane >> 4;
  const int g0 = blockIdx.x * 64;
  const int ks = blockIdx.y;
  f32x4 acc[8];
  #pragma unroll
  for (int i = 0; i < 8; i++) acc[i] = f32x4{0.f,0.f,0.f,0.f};

  for (int ch = 0; ch < 8; ch++) {
    int pb  = ks*256 + ch*32;       // pair-word base within h row
    int kk0 = ks*512 + ch*64;       // fp32 k base in W1
    #pragma unroll
    for (int i = 0; i < 2; i++) {
      int idx = tid + i*256; int r = idx >> 3, q4 = idx & 7;
      uint4 v = *(const uint4*)&hbuf[(size_t)(g0+r)*4096 + pb + q4*4];
      *(uint4*)&sAh[(r<<5) | ((q4 ^ (r & 7))<<2)] = v;
    }
    #pragma unroll
    for (int i = 0; i < 16; i++) {
      int idx = tid + i*256;        // 4096 pair slots
      int c = idx & 127, kp = idx >> 7;
      int kk = kk0 + 2*kp;
      sBh[oswz(c, kp)] = pkh(W1[(size_t)kk*128 + c], W1[(size_t)(kk+1)*128 + c]);
    }
    __syncthreads();
    U4H8 a0t, a1t;
    a0t.u = *(uint4*)&sAh[obase(16*wv + lw, lq)];
    a1t.u = *(uint4*)&sAh[obase(16*wv + lw, 4+lq)];
    #pragma unroll
    for (int nt = 0; nt < 8; nt++) {
      int c = nt*16 + lw;
      U4H8 b0t, b1t;
      b0t.u = *(uint4*)&sBh[obase(c, lq)];
      b1t.u = *(uint4*)&sBh[obase(c, 4+lq)];
      acc[nt] = MFMA16H(a0t.h, b0t.h, acc[nt], 0, 0, 0);
      acc[nt] = MFMA16H(a1t.h, b1t.h, acc[nt], 0, 0, 0);
    }
    __syncthreads();
  }
  float* pp = partial + (size_t)ks*131072;
  #pragma unroll
  for (int nt = 0; nt < 8; nt++) {
    int c = nt*16 + lw;
    int r0 = g0 + 16*wv + lq*4;
    #pragma unroll
    for (int rg = 0; rg < 4; rg++)
      pp[(size_t)(r0+rg)*128 + c] = acc[nt][rg];
  }
}

// ---------------- head epilogue: 8 graphs/block, float4 coalesced ----------------
__global__ __launch_bounds__(256) void head_out(
    const float* __restrict__ partial, const float* __restrict__ b1,
    const float* __restrict__ W2, const float* __restrict__ b2,
    float* __restrict__ out)
{
  const int tid = threadIdx.x;
  const int gl  = tid >> 5;
  const int c4  = tid & 31;
  const int g   = blockIdx.x*8 + gl;
  float4 v = *(const float4*)&b1[c4*4];
  #pragma unroll
  for (int s = 0; s < 16; s++) {
    float4 p = *(const float4*)&partial[(size_t)s*131072 + (size_t)g*128 + c4*4];
    v.x += p.x; v.y += p.y; v.z += p.z; v.w += p.w;
  }
  float4 w = *(const float4*)&W2[c4*4];
  float t = lrelu(v.x,0.01f)*w.x + lrelu(v.y,0.01f)*w.y
          + lrelu(v.z,0.01f)*w.z + lrelu(v.w,0.01f)*w.w;
  #pragma unroll
  for (int m = 1; m < 32; m <<= 1) t += __shfl_xor(t, m);
  if (c4 == 0) out[g] = 1.f / (1.f + __expf(-(t + b2[0])));
}

extern "C" void kernel_launch(void* const* d_in, const int* in_sizes, int n_in,
                              void* d_out, int out_size, void* d_ws, size_t ws_size,
                              hipStream_t stream) {
  const float* x   = (const float*)d_in[0];
  const int*   ei  = (const int*)  d_in[1];
  const float* Wl  = (const float*)d_in[2];
  const float* bl_ = (const float*)d_in[3];
  const float* Wr  = (const float*)d_in[4];
  const float* br_ = (const float*)d_in[5];
  const float* att = (const float*)d_in[6];
  const float* bv2 = (const float*)d_in[7];
  const float* Wg1 = (const float*)d_in[8];
  const float* as1 = (const float*)d_in[9];
  const float* ad1 = (const float*)d_in[10];
  const float* bg1 = (const float*)d_in[11];
  const float* Wg2 = (const float*)d_in[12];
  const float* as2 = (const float*)d_in[13];
  const float* ad2 = (const float*)d_in[14];
  const float* bg2 = (const float*)d_in[15];
  const float* lng = (const float*)d_in[16];
  const float* lnb = (const float*)d_in[17];
  const float* W1  = (const float*)d_in[18];
  const float* b1  = (const float*)d_in[19];
  const float* W2  = (const float*)d_in[20];
  const float* b2  = (const float*)d_in[21];
  float* out = (float*)d_out;

  uint*  hbuf    = (uint*)d_ws;                                      // 16 MB (fp16 pairs)
  float* partial = (float*)((char*)d_ws + (size_t)16*1024*1024);     // 8 MB

  gnn_fused<<<NGRAPH, 256, 0, stream>>>(x, ei, Wl, bl_, Wr, br_, att, bv2,
      Wg1, as1, ad1, bg1, Wg2, as2, ad2, bg2, lng, lnb, hbuf);
  head_gemm<<<dim3(16, 16), 256, 0, stream>>>(hbuf, W1, partial);
  head_out<<<128, 256, 0, stream>>>(partial, b1, W2, b2, out);
}

// Round 8
// 301.604 us; speedup vs baseline: 1.0436x; 1.0284x over previous
//
#include <hip/hip_runtime.h>
#include <hip/hip_bf16.h>
#include <hip/hip_fp16.h>

#define NGRAPH 1024
#define NPG 128
#define EPG 2048
#define ETOT (NGRAPH*NPG*16)

typedef unsigned int uint;
typedef unsigned short ushort_t;
typedef __attribute__((ext_vector_type(2))) _Float16 h2v;
typedef __attribute__((ext_vector_type(8))) _Float16 h8v;
typedef __attribute__((ext_vector_type(4))) float f32x4;

#define MFMA16H __builtin_amdgcn_mfma_f32_16x16x32_f16
#define FDOT2(a,b,c) __builtin_amdgcn_fdot2((a),(b),(c),false)

union U1H2 { uint u; h2v h; };
union U4H8 { uint4 u; h8v h; };
union U4H2 { uint4 u; h2v h[4]; };

__device__ __forceinline__ float lrelu(float x, float s){ return fmaxf(x, x*s); }
__device__ __forceinline__ uint pkh(float a, float b){
  U1H2 t; t.h.x = (_Float16)a; t.h.y = (_Float16)b; return t.u;
}
__device__ __forceinline__ ushort_t hfb(float v){
  union { _Float16 h; ushort_t u; } t; t.h = (_Float16)v; return t.u;
}
__device__ __forceinline__ float2 uph(uint u){
  U1H2 t; t.u = u;
  return float2{(float)t.h.x, (float)t.h.y};
}
#define DPP_ADD(v, ctrl) ((v) + __int_as_float(__builtin_amdgcn_update_dpp(0, __float_as_int(v), (ctrl), 0xF, 0xF, false)))

// fp16 rows of 64 feats (32 u32 pair-words), octet-XOR swizzle
__device__ __forceinline__ int oswz(int r, int p){ return (r<<5) | ((((p>>2) ^ (r & 7))<<2) | (p & 3)); }
__device__ __forceinline__ int obase(int r, int oc){ return (r<<5) | (((oc) ^ (r & 7))<<2); }

__device__ __forceinline__ void fma8(float* acc, uint4 q, float a){
  float2 f0 = uph(q.x), f1 = uph(q.y), f2 = uph(q.z), f3 = uph(q.w);
  acc[0] += a*f0.x; acc[1] += a*f0.y;
  acc[2] += a*f1.x; acc[3] += a*f1.y;
  acc[4] += a*f2.x; acc[5] += a*f2.y;
  acc[6] += a*f3.x; acc[7] += a*f3.y;
}

// LDS map (u32 words): 11713 w = 46852 B -> 3 blocks/CU
#define O_A   0        // 4096: xl / xw        ROW32 [128][32]
#define O_B   4096     // 4096: xr -> h chain  ROW32 [128][32]
#define O_EVA 8192     // 2048: eva f32[2048] / WgT f16 [64][32pairs] / spos int[128]
#define O_ED  10240    // 1024: edsd u16[2048]
#define O_WS  11264    // 128: was[64]+wad[64]
#define O_SOF 11392    // 65:  soff u16[130]
#define O_ALS 11457    // 128: us / 1-sum / selfw
#define O_ALD 11585    // 128: wd / rnm
#define SM_SZ 11713

__global__ __launch_bounds__(256, 3) void gnn_fused(
    const float* __restrict__ x, const int* __restrict__ ei,
    const float* __restrict__ Wl, const float* __restrict__ bl,
    const float* __restrict__ Wr, const float* __restrict__ br,
    const float* __restrict__ att, const float* __restrict__ bv2,
    const float* __restrict__ Wg1, const float* __restrict__ as1,
    const float* __restrict__ ad1, const float* __restrict__ bg1,
    const float* __restrict__ Wg2, const float* __restrict__ as2,
    const float* __restrict__ ad2, const float* __restrict__ bg2,
    const float* __restrict__ lng, const float* __restrict__ lnb,
    uint* __restrict__ hout)
{
  __shared__ uint SM[SM_SZ];
  float*    eva    = (float*)(SM + O_EVA);
  ushort_t* edsL   = (ushort_t*)(SM + O_ED);
  ushort_t* soff16 = (ushort_t*)(SM + O_SOF);
  float*    als    = (float*)(SM + O_ALS);
  float*    ald    = (float*)(SM + O_ALD);
  float*    was    = (float*)(SM + O_WS);
  float*    wad    = was + 64;
  ushort_t* wgA16  = (ushort_t*)(SM + O_A);
  ushort_t* wg16   = (ushort_t*)(SM + O_EVA);

  const int g    = blockIdx.x;
  const int tid  = threadIdx.x;
  const int lane = tid & 63;
  const int wv   = tid >> 6;
  const int lw   = lane & 15;
  const int lq   = lane >> 4;
  const int sl   = lane & 7;
  const int grp  = lane >> 3;
  const int ebase = g * EPG;

  // ================= CSR build =================
  {
    int* spos = (int*)(SM + O_EVA);
    if (tid < NPG) spos[tid] = 0;
    __syncthreads();
    for (int e = tid; e < EPG; e += 256)
      atomicAdd(&spos[ei[ETOT + ebase + e] - g*NPG], 1);
    __syncthreads();
    if (wv == 0) {
      int c0 = spos[lane], c1 = spos[lane + 64];
      #pragma unroll
      for (int o = 1; o < 64; o <<= 1) { int t = __shfl_up(c0, o); if (lane >= o) c0 += t; }
      #pragma unroll
      for (int o = 1; o < 64; o <<= 1) { int t = __shfl_up(c1, o); if (lane >= o) c1 += t; }
      int tot0 = __shfl(c0, 63);
      soff16[lane + 1]  = (ushort_t)c0;
      soff16[lane + 65] = (ushort_t)(c1 + tot0);
      if (lane == 0) soff16[0] = 0;
    }
    __syncthreads();
    if (tid < NPG) spos[tid] = soff16[tid];
    __syncthreads();
    for (int e = tid; e < EPG; e += 256) {
      int s = ei[ebase + e] - g*NPG;
      int d = ei[ETOT + ebase + e] - g*NPG;
      int p = atomicAdd(&spos[d], 1);
      edsL[p] = (ushort_t)(s | (d << 8));
    }
  }

  // ================= GATv2 transforms: xl -> O_A, xr -> O_B (fp16) =================
  {
    const int pl = lane & 31, hb = lane >> 5;
    const float2 wl0 = *(const float2*)&Wl[0*64 + 2*pl];
    const float2 wl1 = *(const float2*)&Wl[1*64 + 2*pl];
    const float2 wl2 = *(const float2*)&Wl[2*64 + 2*pl];
    const float2 wl3 = *(const float2*)&Wl[3*64 + 2*pl];
    const float2 wr0 = *(const float2*)&Wr[0*64 + 2*pl];
    const float2 wr1 = *(const float2*)&Wr[1*64 + 2*pl];
    const float2 wr2 = *(const float2*)&Wr[2*64 + 2*pl];
    const float2 wr3 = *(const float2*)&Wr[3*64 + 2*pl];
    const float2 blp = *(const float2*)&bl[2*pl];
    const float2 brp = *(const float2*)&br[2*pl];
    const float4* x4 = (const float4*)x + (size_t)g * NPG;
    for (int st = 0; st < 16; st++) {
      int i = st*8 + wv*2 + hb;
      float4 xi = x4[i];
      float l0 = blp.x + xi.x*wl0.x + xi.y*wl1.x + xi.z*wl2.x + xi.w*wl3.x;
      float l1 = blp.y + xi.x*wl0.y + xi.y*wl1.y + xi.z*wl2.y + xi.w*wl3.y;
      float r0 = brp.x + xi.x*wr0.x + xi.y*wr1.x + xi.z*wr2.x + xi.w*wr3.x;
      float r1 = brp.y + xi.x*wr0.y + xi.y*wr1.y + xi.z*wr2.y + xi.w*wr3.y;
      SM[O_A + oswz(i, pl)] = pkh(l0, l1);
      SM[O_B + oswz(i, pl)] = pkh(r0, r1);
    }
  }
  __syncthreads();   // covers CSR scatter + transforms

  // per-thread att fragments for my octet
  h2v a06[4], a04[4];
  #pragma unroll
  for (int q2 = 0; q2 < 4; q2++) {
    float2 a = *(const float2*)&att[sl*8 + 2*q2];
    a06[q2].x = (_Float16)(0.6f*a.x); a06[q2].y = (_Float16)(0.6f*a.y);
    a04[q2].x = (_Float16)(0.4f*a.x); a04[q2].y = (_Float16)(0.4f*a.y);
  }

  // ================= GATv2 rank-1 node terms: als <- 0.6 att.xl, ald <- 0.6 att.xr
  for (int ps = 0; ps < 4; ps++) {
    int n = ps*32 + (tid >> 3);
    U4H2 ql; ql.u = *(uint4*)&SM[O_A + obase(n, sl)];
    U4H2 qr; qr.u = *(uint4*)&SM[O_B + obase(n, sl)];
    float su = 0.f, sw = 0.f;
    #pragma unroll
    for (int q2 = 0; q2 < 4; q2++) {
      su = FDOT2(ql.h[q2], a06[q2], su);
      sw = FDOT2(qr.h[q2], a06[q2], sw);
    }
    su = DPP_ADD(su, 0x111); su = DPP_ADD(su, 0x112); su = DPP_ADD(su, 0x114);
    sw = DPP_ADD(sw, 0x111); sw = DPP_ADD(sw, 0x112); sw = DPP_ADD(sw, 0x114);
    if ((lane & 7) == 7) { als[n] = su; ald[n] = sw; }
  }
  __syncthreads();

  // ================= GATv2 edge logits: group-per-edge, abs-term + rank-1 ======
  {
    for (int step = 0; step < 64; step++) {
      int e  = wv*512 + step*8 + grp;
      int sd = edsL[e];
      int s  = sd & 127, d = sd >> 8;
      U4H2 ql; ql.u = *(uint4*)&SM[O_A + obase(s, sl)];
      U4H2 qr; qr.u = *(uint4*)&SM[O_B + obase(d, sl)];
      float acc = 0.f;
      #pragma unroll
      for (int q2 = 0; q2 < 4; q2++) {
        h2v v = ql.h[q2] + qr.h[q2];
        U1H2 t; t.h = v; t.u &= 0x7FFF7FFFu;
        acc = FDOT2(t.h, a04[q2], acc);
      }
      acc = DPP_ADD(acc, 0x111); acc = DPP_ADD(acc, 0x112); acc = DPP_ADD(acc, 0x114);
      if (sl == 7) eva[e] = acc + als[s] + ald[d];
    }
  }
  __syncthreads();

  // ================= GATv2 softmax (16 lanes/dst): eva <- exp, als <- 1/sum ======
  {
    const int dd = tid >> 4, sl16 = tid & 15;
    for (int it = 0; it < 8; it++) {
      int d = it*16 + dd;
      int p0 = soff16[d], p1 = soff16[d+1];
      float m = -1e30f;
      for (int p = p0 + sl16; p < p1; p += 16) m = fmaxf(m, eva[p]);
      #pragma unroll
      for (int o = 1; o < 16; o <<= 1) m = fmaxf(m, __shfl_xor(m, o));
      float ss = 0.f;
      for (int p = p0 + sl16; p < p1; p += 16) {
        float ex = __expf(eva[p] - m); ss += ex; eva[p] = ex;
      }
      #pragma unroll
      for (int o = 1; o < 16; o <<= 1) ss += __shfl_xor(ss, o);
      if (sl16 == 0) als[d] = 1.f / (ss + 1e-16f);
    }
  }
  __syncthreads();

  // ================= GATv2 aggregate (group/dst, f32 accum — feeds LN) ==========
  {
    float2 bvA = *(const float2*)&bv2[sl*8];
    float2 bvB = *(const float2*)&bv2[sl*8 + 2];
    float2 bvC = *(const float2*)&bv2[sl*8 + 4];
    float2 bvD = *(const float2*)&bv2[sl*8 + 6];
    for (int pass = 0; pass < 4; pass++) {
      int d  = wv*32 + pass*8 + grp;
      int p0 = soff16[d], p1 = soff16[d+1];
      float acc[8] = {0,0,0,0,0,0,0,0};
      if (p0 < p1) {
        int sN = edsL[p0] & 127;
        uint4 qN = *(uint4*)&SM[O_A + obase(sN, sl)];
        float wN = eva[p0];
        for (int e = p0; e < p1; e++) {
          uint4 ql = qN; float w = wN;
          if (e + 1 < p1) {
            sN = edsL[e+1] & 127;
            qN = *(uint4*)&SM[O_A + obase(sN, sl)];
            wN = eva[e+1];
          }
          fma8(acc, ql, w);
        }
      }
      float nm = als[d];
      uint4 o;
      o.x = pkh(lrelu(acc[0]*nm+bvA.x,0.01f), lrelu(acc[1]*nm+bvA.y,0.01f));
      o.y = pkh(lrelu(acc[2]*nm+bvB.x,0.01f), lrelu(acc[3]*nm+bvB.y,0.01f));
      o.z = pkh(lrelu(acc[4]*nm+bvC.x,0.01f), lrelu(acc[5]*nm+bvC.y,0.01f));
      o.w = pkh(lrelu(acc[6]*nm+bvD.x,0.01f), lrelu(acc[7]*nm+bvD.y,0.01f));
      *(uint4*)&SM[O_B + obase(d, sl)] = o;
    }
  }
  __syncthreads();

  // ================= LayerNorm in place on O_B (fdot2 sums) =================
  {
    int pl = lane & 31, hb = lane >> 5;
    float2 gv = *(const float2*)&lng[2*pl];
    float2 bv = *(const float2*)&lnb[2*pl];
    h2v one2; one2.x = (_Float16)1.f; one2.y = (_Float16)1.f;
    for (int it = 0; it < 16; it++) {
      int d = it*8 + wv*2 + hb;
      uint w = SM[O_B + oswz(d, pl)];
      U1H2 t; t.u = w;
      float s1 = FDOT2(t.h, one2, 0.f);
      float s2 = FDOT2(t.h, t.h, 0.f);
      #pragma unroll
      for (int o = 1; o < 32; o <<= 1) { s1 += __shfl_xor(s1, o); s2 += __shfl_xor(s2, o); }
      float mu  = s1 * 0.015625f;
      float var = s2 * 0.015625f - mu*mu;
      float rs  = rsqrtf(var + 1e-5f);
      float2 f = uph(w);
      SM[O_B + oswz(d, pl)] = pkh((f.x-mu)*rs*gv.x + bv.x, (f.y-mu)*rs*gv.y + bv.y);
    }
  }
  __syncthreads();

  // ================= two GATConv layers =================
  for (int layer = 0; layer < 2; layer++) {
    const float* Wg  = layer ? Wg2 : Wg1;
    const float* avs = layer ? as2 : as1;
    const float* avd = layer ? ad2 : ad1;
    const float* bg  = layer ? bg2 : bg1;

    // --- stage: was/wad = Wg @ a ; WgT fp16 -> eva region
    if (tid < 128) {
      const float* av = (tid < 64) ? avs : avd;
      float* dst = (tid < 64) ? was : wad;
      int k = tid & 63;
      float acc = 0.f;
      #pragma unroll
      for (int jj = 0; jj < 16; jj++) {
        float4 w = *(const float4*)&Wg[k*64 + jj*4];
        float4 a = *(const float4*)&av[jj*4];
        acc += w.x*a.x + w.y*a.y + w.z*a.z + w.w*a.w;
      }
      dst[k] = acc;
    } else {
      int t2 = tid - 128;
      #pragma unroll
      for (int i = 0; i < 8; i++) {
        int idx = t2 + i*128;
        int k = idx >> 4, j4 = (idx & 15)*4;
        float4 w = *(const float4*)&Wg[k*64 + j4];
        wg16[oswz(j4+0, k>>1)*2 + (k&1)] = hfb(w.x);
        wg16[oswz(j4+1, k>>1)*2 + (k&1)] = hfb(w.y);
        wg16[oswz(j4+2, k>>1)*2 + (k&1)] = hfb(w.z);
        wg16[oswz(j4+3, k>>1)*2 + (k&1)] = hfb(w.w);
      }
    }
    __syncthreads();

    // --- MFMA transform xw = h @ Wg -> O_A ; rank-1 als/ald via fdot2
    {
      U4H8 a0t, a1t;
      a0t.u = *(uint4*)&SM[O_EVA + obase(16*wv + lw, lq)];
      a1t.u = *(uint4*)&SM[O_EVA + obase(16*wv + lw, 4+lq)];
      int j0 = 16*wv + lq*4;
      #pragma unroll
      for (int nt = 0; nt < 8; nt++) {
        int d = nt*16 + lw;
        U4H8 b0t, b1t;
        b0t.u = *(uint4*)&SM[O_B + obase(d, lq)];
        b1t.u = *(uint4*)&SM[O_B + obase(d, 4+lq)];
        f32x4 c = {0.f,0.f,0.f,0.f};
        c = MFMA16H(a0t.h, b0t.h, c, 0, 0, 0);
        c = MFMA16H(a1t.h, b1t.h, c, 0, 0, 0);
        #pragma unroll
        for (int rg = 0; rg < 4; rg++) {
          int j = j0 + rg;
          wgA16[oswz(d, j>>1)*2 + (j&1)] = hfb(c[rg]);
        }
      }
      // rank-1 attention halves (fdot2 over fp16 pairs)
      h2v ws2[4], wd2[4];
      #pragma unroll
      for (int q2 = 0; q2 < 4; q2++) {
        float2 a = *(float2*)&was[sl*8 + 2*q2];
        float2 b = *(float2*)&wad[sl*8 + 2*q2];
        ws2[q2].x = (_Float16)a.x; ws2[q2].y = (_Float16)a.y;
        wd2[q2].x = (_Float16)b.x; wd2[q2].y = (_Float16)b.y;
      }
      for (int ps = 0; ps < 4; ps++) {
        int n = ps*32 + (tid >> 3);
        U4H2 q; q.u = *(uint4*)&SM[O_B + obase(n, sl)];
        float sa = 0.f, sd = 0.f;
        #pragma unroll
        for (int q2 = 0; q2 < 4; q2++) {
          sa = FDOT2(q.h[q2], ws2[q2], sa);
          sd = FDOT2(q.h[q2], wd2[q2], sd);
        }
        sa = DPP_ADD(sa, 0x111); sa = DPP_ADD(sa, 0x112); sa = DPP_ADD(sa, 0x114);
        sd = DPP_ADD(sd, 0x111); sd = DPP_ADD(sd, 0x112); sd = DPP_ADD(sd, 0x114);
        if ((lane & 7) == 7) { als[n] = sa; ald[n] = sd; }
      }
    }
    __syncthreads();

    // --- edge logits EDGE-PARALLEL (rank-1), raw -> eva
    for (int it = 0; it < 8; it++) {
      int e  = tid + it*256;
      int sd = edsL[e];
      eva[e] = lrelu(als[sd & 127] + ald[sd >> 8], 0.2f);
    }
    __syncthreads();

    // --- softmax incl self (16 lanes/dst): eva <- exp, als <- self exp, ald <- 1/sum
    {
      const int dd = tid >> 4, sl16 = tid & 15;
      for (int it = 0; it < 8; it++) {
        int d = it*16 + dd;
        int p0 = soff16[d], p1 = soff16[d+1];
        float lgs = lrelu(als[d] + ald[d], 0.2f);
        float m = lgs;
        for (int p = p0 + sl16; p < p1; p += 16) m = fmaxf(m, eva[p]);
        #pragma unroll
        for (int o = 1; o < 16; o <<= 1) m = fmaxf(m, __shfl_xor(m, o));
        float ex0 = __expf(lgs - m);
        float ss = 0.f;
        for (int p = p0 + sl16; p < p1; p += 16) {
          float ex = __expf(eva[p] - m); ss += ex; eva[p] = ex;
        }
        #pragma unroll
        for (int o = 1; o < 16; o <<= 1) ss += __shfl_xor(ss, o);
        if (sl16 == 0) {
          als[d] = ex0;
          ald[d] = 1.f / (ss + ex0 + 1e-16f);
        }
      }
    }
    __syncthreads();

    // --- aggregate incl self (group/dst, fp16 pk_fma accum), bias+relu -> O_B
    {
      float2 bgA = *(const float2*)&bg[sl*8];
      float2 bgB = *(const float2*)&bg[sl*8 + 2];
      float2 bgC = *(const float2*)&bg[sl*8 + 4];
      float2 bgD = *(const float2*)&bg[sl*8 + 6];
      for (int pass = 0; pass < 4; pass++) {
        int d  = wv*32 + pass*8 + grp;
        int p0 = soff16[d], p1 = soff16[d+1];
        // self term (pk_mul)
        _Float16 hw0 = (_Float16)als[d];
        h2v w2; w2.x = hw0; w2.y = hw0;
        U4H2 acc2, qs;
        qs.u = *(uint4*)&SM[O_A + obase(d, sl)];
        #pragma unroll
        for (int q2 = 0; q2 < 4; q2++) acc2.h[q2] = qs.h[q2] * w2;
        if (p0 < p1) {
          int sN = edsL[p0] & 127;
          uint4 qN = *(uint4*)&SM[O_A + obase(sN, sl)];
          float wN = eva[p0];
          for (int e = p0; e < p1; e++) {
            U4H2 ql; ql.u = qN; float w = wN;
            if (e + 1 < p1) {
              sN = edsL[e+1] & 127;
              qN = *(uint4*)&SM[O_A + obase(sN, sl)];
              wN = eva[e+1];
            }
            _Float16 hw = (_Float16)w;
            h2v we2; we2.x = hw; we2.y = hw;
            #pragma unroll
            for (int q2 = 0; q2 < 4; q2++) acc2.h[q2] += ql.h[q2] * we2;
          }
        }
        float nm = ald[d];
        float2 r0 = uph(acc2.u.x), r1 = uph(acc2.u.y), r2 = uph(acc2.u.z), r3 = uph(acc2.u.w);
        uint4 o;
        o.x = pkh(fmaxf(r0.x*nm+bgA.x,0.f), fmaxf(r0.y*nm+bgA.y,0.f));
        o.y = pkh(fmaxf(r1.x*nm+bgB.x,0.f), fmaxf(r1.y*nm+bgB.y,0.f));
        o.z = pkh(fmaxf(r2.x*nm+bgC.x,0.f), fmaxf(r2.y*nm+bgC.y,0.f));
        o.w = pkh(fmaxf(r3.x*nm+bgD.x,0.f), fmaxf(r3.y*nm+bgD.y,0.f));
        *(uint4*)&SM[O_B + obase(d, sl)] = o;
      }
    }
    __syncthreads();
  }

  // ================= write h (fp16 pairs, node-major) =================
  {
    uint* hg = hout + (size_t)g * 4096;
    #pragma unroll
    for (int i = 0; i < 16; i++) {
      int idx = tid + i*256;
      hg[idx] = SM[O_B + oswz(idx >> 5, idx & 31)];
    }
  }
}

// ---------------- head GEMM: MFMA f16, split-K 32, in-kernel W1 transpose -------
__global__ __launch_bounds__(256) void head_gemm(
    const uint* __restrict__ hbuf, const float* __restrict__ W1,
    float* __restrict__ partial)
{
  __shared__ uint sAh[2048];
  __shared__ uint sBh[4096];
  const int tid = threadIdx.x, lane = tid & 63, wv = tid >> 6;
  const int lw = lane & 15, lq = lane >> 4;
  const int g0 = blockIdx.x * 64;
  const int ks = blockIdx.y;
  f32x4 acc[8];
  #pragma unroll
  for (int i = 0; i < 8; i++) acc[i] = f32x4{0.f,0.f,0.f,0.f};

  for (int ch = 0; ch < 4; ch++) {
    int pb  = ks*128 + ch*32;       // pair-word base within h row
    int kk0 = ks*256 + ch*64;       // fp32 k base in W1
    #pragma unroll
    for (int i = 0; i < 2; i++) {
      int idx = tid + i*256; int r = idx >> 3, q4 = idx & 7;
      uint4 v = *(const uint4*)&hbuf[(size_t)(g0+r)*4096 + pb + q4*4];
      *(uint4*)&sAh[(r<<5) | ((q4 ^ (r & 7))<<2)] = v;
    }
    #pragma unroll
    for (int i = 0; i < 16; i++) {
      int idx = tid + i*256;        // 4096 pair slots
      int c = idx & 127, kp = idx >> 7;
      int kk = kk0 + 2*kp;
      sBh[oswz(c, kp)] = pkh(W1[(size_t)kk*128 + c], W1[(size_t)(kk+1)*128 + c]);
    }
    __syncthreads();
    U4H8 a0t, a1t;
    a0t.u = *(uint4*)&sAh[obase(16*wv + lw, lq)];
    a1t.u = *(uint4*)&sAh[obase(16*wv + lw, 4+lq)];
    #pragma unroll
    for (int nt = 0; nt < 8; nt++) {
      int c = nt*16 + lw;
      U4H8 b0t, b1t;
      b0t.u = *(uint4*)&sBh[obase(c, lq)];
      b1t.u = *(uint4*)&sBh[obase(c, 4+lq)];
      acc[nt] = MFMA16H(a0t.h, b0t.h, acc[nt], 0, 0, 0);
      acc[nt] = MFMA16H(a1t.h, b1t.h, acc[nt], 0, 0, 0);
    }
    __syncthreads();
  }
  float* pp = partial + (size_t)ks*131072;
  #pragma unroll
  for (int nt = 0; nt < 8; nt++) {
    int c = nt*16 + lw;
    int r0 = g0 + 16*wv + lq*4;
    #pragma unroll
    for (int rg = 0; rg < 4; rg++)
      pp[(size_t)(r0+rg)*128 + c] = acc[nt][rg];
  }
}

// ---------------- head epilogue: 8 graphs/block, float4 coalesced ----------------
__global__ __launch_bounds__(256) void head_out(
    const float* __restrict__ partial, const float* __restrict__ b1,
    const float* __restrict__ W2, const float* __restrict__ b2,
    float* __restrict__ out)
{
  const int tid = threadIdx.x;
  const int gl  = tid >> 5;
  const int c4  = tid & 31;
  const int g   = blockIdx.x*8 + gl;
  float4 v = *(const float4*)&b1[c4*4];
  #pragma unroll
  for (int s = 0; s < 32; s++) {
    float4 p = *(const float4*)&partial[(size_t)s*131072 + (size_t)g*128 + c4*4];
    v.x += p.x; v.y += p.y; v.z += p.z; v.w += p.w;
  }
  float4 w = *(const float4*)&W2[c4*4];
  float t = lrelu(v.x,0.01f)*w.x + lrelu(v.y,0.01f)*w.y
          + lrelu(v.z,0.01f)*w.z + lrelu(v.w,0.01f)*w.w;
  #pragma unroll
  for (int m = 1; m < 32; m <<= 1) t += __shfl_xor(t, m);
  if (c4 == 0) out[g] = 1.f / (1.f + __expf(-(t + b2[0])));
}

extern "C" void kernel_launch(void* const* d_in, const int* in_sizes, int n_in,
                              void* d_out, int out_size, void* d_ws, size_t ws_size,
                              hipStream_t stream) {
  const float* x   = (const float*)d_in[0];
  const int*   ei  = (const int*)  d_in[1];
  const float* Wl  = (const float*)d_in[2];
  const float* bl_ = (const float*)d_in[3];
  const float* Wr  = (const float*)d_in[4];
  const float* br_ = (const float*)d_in[5];
  const float* att = (const float*)d_in[6];
  const float* bv2 = (const float*)d_in[7];
  const float* Wg1 = (const float*)d_in[8];
  const float* as1 = (const float*)d_in[9];
  const float* ad1 = (const float*)d_in[10];
  const float* bg1 = (const float*)d_in[11];
  const float* Wg2 = (const float*)d_in[12];
  const float* as2 = (const float*)d_in[13];
  const float* ad2 = (const float*)d_in[14];
  const float* bg2 = (const float*)d_in[15];
  const float* lng = (const float*)d_in[16];
  const float* lnb = (const float*)d_in[17];
  const float* W1  = (const float*)d_in[18];
  const float* b1  = (const float*)d_in[19];
  const float* W2  = (const float*)d_in[20];
  const float* b2  = (const float*)d_in[21];
  float* out = (float*)d_out;

  uint*  hbuf    = (uint*)d_ws;                                      // 16 MB (fp16 pairs)
  float* partial = (float*)((char*)d_ws + (size_t)16*1024*1024);     // 16 MB (32 slices)

  gnn_fused<<<NGRAPH, 256, 0, stream>>>(x, ei, Wl, bl_, Wr, br_, att, bv2,
      Wg1, as1, ad1, bg1, Wg2, as2, ad2, bg2, lng, lnb, hbuf);
  head_gemm<<<dim3(16, 32), 256, 0, stream>>>(hbuf, W1, partial);
  head_out<<<128, 256, 0, stream>>>(partial, b1, W2, b2, out);
}